// Round 11
// baseline (292.150 us; speedup 1.0000x reference)
//
#include <hip/hip_runtime.h>
#include <cstdint>
#include <cstddef>

namespace {

constexpr int N_NODES = 100000;
constexpr int N_EDGES = 1600000;
constexpr int NUM_GRAPHS = 128;
constexpr int F = 128;
constexpr float BN_EPS = 1e-5f;

// bucket sort params: 196 buckets x 512 nodes; 400 chunks x 4000 edges
constexpr int W_BUCK = 512;
constexpr int NBUCK = (N_NODES + W_BUCK - 1) / W_BUCK;  // 196
constexpr int CB = 400;
constexpr int CHUNK = N_EDGES / CB;                      // 4000

// R10: slotted stats (atomic serialization was the 47us floor — confirmed,
// 310->271). R11: layer-1 stats via 16x16 Gram matrix accumulated in k_rank
// (h1 is linear in z=xa[0:16]; sumsq_f = w^T G w + 2b(w.S) + N b^2) -> the
// whole k_lin1s dispatch is deleted.
constexpr int SL2 = 8;                         // layer-2 stats slots
constexpr int GSL = 16;                        // gram slots
constexpr int GST = 152;                       // 136 tri + 16 S
constexpr int GRAM_FLOATS = GSL * GST;         // 2432
constexpr int ZTOT = GRAM_FLOATS + SL2 * 256 + NUM_GRAPHS * F;  // 20864

typedef float f32x4 __attribute__((ext_vector_type(4)));
typedef float f32x2 __attribute__((ext_vector_type(2)));
typedef short s16x8 __attribute__((ext_vector_type(8)));
typedef unsigned char uchar;
union B8 { uint4 u; s16x8 s; };

__device__ inline ushort f2bf(float x) {         // RNE fp32 -> bf16
    uint u = __float_as_uint(x);
    u += 0x7fffu + ((u >> 16) & 1u);
    return (ushort)(u >> 16);
}
__device__ inline float bf2f(ushort s) { return __uint_as_float(((uint)s) << 16); }
__device__ inline uint pack2(float lo, float hi) {
    return (uint)f2bf(lo) | ((uint)f2bf(hi) << 16);
}
__device__ inline float bflo(uint u) { return __uint_as_float(u << 16); }
__device__ inline float bfhi(uint u) { return __uint_as_float(u & 0xffff0000u); }

// accumulate 4 fp8 (one u32) into a[0..3] via HW cvt
__device__ inline void acc4f8(float* a, uint u) {
    f32x2 lo = __builtin_amdgcn_cvt_pk_f32_fp8((int)u, false);
    f32x2 hi = __builtin_amdgcn_cvt_pk_f32_fp8((int)u, true);
    a[0] += lo[0]; a[1] += lo[1]; a[2] += hi[0]; a[3] += hi[1];
}
// accumulate one bf16x8 row (uint4) into a[0..7]
__device__ inline void acc8bf(float* a, uint4 v) {
    a[0] += bflo(v.x); a[1] += bfhi(v.x);
    a[2] += bflo(v.y); a[3] += bfhi(v.y);
    a[4] += bflo(v.z); a[5] += bfhi(v.z);
    a[6] += bflo(v.w); a[7] += bfhi(v.w);
}

// ---- k_pre: histA + bound + weight packs + xbf + zero-fills (one dispatch) --

constexpr int PB_HIST  = CB;                       // 400
constexpr int PB_BOUND = (N_NODES + 255) / 256;    // 391
constexpr int PB_PB    = 64;
constexpr int PB_PB1   = 16;
constexpr int PB_PX    = (N_NODES + 255) / 256;    // 391
constexpr int PB_Z     = (ZTOT + 255) / 256;       // 82
constexpr int PB_TOTAL = PB_HIST + PB_BOUND + PB_PB + PB_PB1 + PB_PX + PB_Z;

__global__ void __launch_bounds__(256) k_pre(
        const int* __restrict__ ei, int* __restrict__ gcount,
        const int* __restrict__ batch, int* __restrict__ gstart,
        const float* __restrict__ W2l, const float* __restrict__ W2r,
        ushort* __restrict__ Wcat,
        const float* __restrict__ W1l, const float* __restrict__ W1r,
        ushort* __restrict__ Wcat1,
        const float* __restrict__ x, ushort* __restrict__ xbf,
        float* __restrict__ zbase) {           // gram | stats2s | outacc
    __shared__ int bins[NBUCK];
    int bid = blockIdx.x, t = threadIdx.x;
    if (bid < PB_HIST) {                        // edge-chunk dst histogram
        for (int i = t; i < NBUCK; i += 256) bins[i] = 0;
        __syncthreads();
        int e0 = bid * CHUNK;
        for (int i = t; i < CHUNK; i += 256)
            atomicAdd(&bins[ei[N_EDGES + e0 + i] >> 9], 1);
        __syncthreads();
        for (int i = t; i < NBUCK; i += 256) gcount[i * CB + bid] = bins[i];
        return;
    }
    bid -= PB_HIST;
    if (bid < PB_BOUND) {                       // graph boundaries
        int i = bid * 256 + t;
        if (i >= N_NODES) return;
        int b = batch[i];
        if (i == 0) {
            for (int g = 0; g <= b; ++g) gstart[g] = 0;
        } else {
            int p = batch[i - 1];
            if (p != b) for (int g = p + 1; g <= b; ++g) gstart[g] = i;
        }
        if (i == N_NODES - 1) {
            for (int g = b + 1; g <= NUM_GRAPHS; ++g) gstart[g] = N_NODES;
        }
        return;
    }
    bid -= PB_BOUND;
    if (bid < PB_PB) {                          // Wcat (layer 2 weights, bf16)
        int i = bid * 256 + t;                  // 16384 exact
        int f = i >> 7, k = i & 127;
        Wcat[f * 256 + k]       = f2bf(W2l[i]);
        Wcat[f * 256 + 128 + k] = f2bf(W2r[i]);
        return;
    }
    bid -= PB_PB;
    if (bid < PB_PB1) {                         // Wcat1 (layer 1 weights)
        int i = bid * 256 + t;                  // 4096 exact
        int f = i >> 5, k = i & 31;
        float v = (k < 8) ? W1r[f * 8 + k] : ((k < 16) ? W1l[f * 8 + (k - 8)] : 0.f);
        Wcat1[i] = f2bf(v);
        return;
    }
    bid -= PB_PB1;
    if (bid < PB_PX) {                          // xbf: bf16 copy of x (16B rows)
        int n = bid * 256 + t;
        if (n >= N_NODES) return;
        const float4* xp = (const float4*)(x + (size_t)n * 8);
        float4 x0 = xp[0], x1 = xp[1];
        uint4 o = {pack2(x0.x, x0.y), pack2(x0.z, x0.w),
                   pack2(x1.x, x1.y), pack2(x1.z, x1.w)};
        *(uint4*)(xbf + (size_t)n * 8) = o;
        return;
    }
    bid -= PB_PX;
    {                                           // zero gram + stats2s + outacc
        int i = bid * 256 + t;
        if (i < ZTOT) zbase[i] = 0.f;
    }
}

// ---- CSR-by-dst via 2-level bucket sort (no global atomics) -----------------

__global__ void __launch_bounds__(512) k_scanA(int* __restrict__ g,
                                               int* __restrict__ bsum) {
    __shared__ int tmp[512];
    int b = blockIdx.x, t = threadIdx.x;
    int v = (t < CB) ? g[b * CB + t] : 0;
    tmp[t] = v;
    __syncthreads();
    #pragma unroll
    for (int d = 1; d < 512; d <<= 1) {
        int u = (t >= d) ? tmp[t - d] : 0;
        __syncthreads();
        tmp[t] += u;
        __syncthreads();
    }
    if (t < CB) g[b * CB + t] = tmp[t] - v;   // local exclusive prefix
    if (t == 511) bsum[b] = tmp[511];         // bucket total (RAW, not scanned)
}

__global__ void __launch_bounds__(256) k_part(const int* __restrict__ ei,
                                              const int* __restrict__ gloc,
                                              const int* __restrict__ bsum,
                                              uint* __restrict__ epk) {
    __shared__ int cur[NBUCK];
    __shared__ int pref[256];
    int t = threadIdx.x;
    int v = (t < NBUCK) ? bsum[t] : 0;        // raw totals
    pref[t] = v;
    __syncthreads();
    #pragma unroll
    for (int d = 1; d < 256; d <<= 1) {
        int u = (t >= d) ? pref[t - d] : 0;
        __syncthreads();
        pref[t] += u;
        __syncthreads();
    }
    if (t < NBUCK) cur[t] = gloc[t * CB + blockIdx.x] + (pref[t] - v); // excl
    __syncthreads();
    int e0 = blockIdx.x * CHUNK;
    for (int i = t; i < CHUNK; i += 256) {
        int d = ei[N_EDGES + e0 + i];
        int s = ei[e0 + i];
        int p = atomicAdd(&cur[d >> 9], 1);
        epk[p] = ((uint)s << 9) | (uint)(d & 511);
    }
}

// k_rank: per-bucket dst ranking + scatter, fused layer-1 mean-gather, and
// (R11) Gram/S accumulation for layer-1 BN stats. No early returns: all 512
// threads reach the wave-shuffle reductions (exited-lane shfl is undefined).
__global__ void __launch_bounds__(512) k_rank(const uint* __restrict__ epk,
                                              const int* __restrict__ bsum,
                                              int* __restrict__ offs,
                                              int* __restrict__ ssrc,
                                              const float* __restrict__ x,
                                              const ushort* __restrict__ xbf,
                                              ushort* __restrict__ xa,
                                              float* __restrict__ gram1s) {
    __shared__ int dcnt[W_BUCK];
    __shared__ int tmp[W_BUCK];
    __shared__ int cur[W_BUCK];
    __shared__ int pref[256];
    __shared__ float sG[GST];
    int b = blockIdx.x, t = threadIdx.x;
    // local scan of raw bucket totals -> inclusive prefix (folded scanB)
    if (t < 256) pref[t] = (t < NBUCK) ? bsum[t] : 0;
    __syncthreads();
    #pragma unroll
    for (int d = 1; d < 256; d <<= 1) {
        int u = (t < 256 && t >= d) ? pref[t - d] : 0;
        __syncthreads();
        if (t < 256) pref[t] += u;
        __syncthreads();
    }
    int s0 = pref[b] - bsum[b];                // exclusive start
    int s1 = pref[b];                          // end
    dcnt[t] = 0;
    if (t < GST) sG[t] = 0.f;
    __syncthreads();
    for (int i = s0 + t; i < s1; i += 512)
        atomicAdd(&dcnt[epk[i] & 511u], 1);
    __syncthreads();
    int v = dcnt[t];
    tmp[t] = v;
    __syncthreads();
    #pragma unroll
    for (int d = 1; d < 512; d <<= 1) {
        int u = (t >= d) ? tmp[t - d] : 0;
        __syncthreads();
        tmp[t] += u;
        __syncthreads();
    }
    int start = s0 + tmp[t] - v;               // exclusive prefix
    int node = b * W_BUCK + t;
    if (node <= N_NODES) offs[node] = start;   // node==N_NODES: writes offs end
    cur[t] = start;
    __syncthreads();
    for (int i = s0 + t; i < s1; i += 512) {
        uint u = epk[i];
        int p = atomicAdd(&cur[u & 511u], 1);
        ssrc[p] = (int)(u >> 9);
    }

    // ---- fused layer-1 aggregation + z for node (thread t owns b*512+t) ----
    __syncthreads();                           // vmcnt(0) drain: ssrc visible
    float z[16];
    #pragma unroll
    for (int i = 0; i < 16; ++i) z[i] = 0.f;
    if (node < N_NODES) {
        int gs = start, ge = start + v;
        float a[8];
        #pragma unroll
        for (int i = 0; i < 8; ++i) a[i] = 0.f;
        int j = gs;
        for (; j + 7 < ge; j += 8) {           // 8 gathers in flight
            int i0 = ssrc[j],   i1 = ssrc[j+1], i2 = ssrc[j+2], i3 = ssrc[j+3];
            int i4 = ssrc[j+4], i5 = ssrc[j+5], i6 = ssrc[j+6], i7 = ssrc[j+7];
            uint4 v0 = *(const uint4*)(xbf + (size_t)i0 * 8);
            uint4 v1 = *(const uint4*)(xbf + (size_t)i1 * 8);
            uint4 v2 = *(const uint4*)(xbf + (size_t)i2 * 8);
            uint4 v3 = *(const uint4*)(xbf + (size_t)i3 * 8);
            uint4 v4 = *(const uint4*)(xbf + (size_t)i4 * 8);
            uint4 v5 = *(const uint4*)(xbf + (size_t)i5 * 8);
            uint4 v6 = *(const uint4*)(xbf + (size_t)i6 * 8);
            uint4 v7 = *(const uint4*)(xbf + (size_t)i7 * 8);
            acc8bf(a, v0); acc8bf(a, v1); acc8bf(a, v2); acc8bf(a, v3);
            acc8bf(a, v4); acc8bf(a, v5); acc8bf(a, v6); acc8bf(a, v7);
        }
        for (; j + 3 < ge; j += 4) {
            int i0 = ssrc[j], i1 = ssrc[j+1], i2 = ssrc[j+2], i3 = ssrc[j+3];
            uint4 v0 = *(const uint4*)(xbf + (size_t)i0 * 8);
            uint4 v1 = *(const uint4*)(xbf + (size_t)i1 * 8);
            uint4 v2 = *(const uint4*)(xbf + (size_t)i2 * 8);
            uint4 v3 = *(const uint4*)(xbf + (size_t)i3 * 8);
            acc8bf(a, v0); acc8bf(a, v1); acc8bf(a, v2); acc8bf(a, v3);
        }
        for (; j < ge; ++j)
            acc8bf(a, *(const uint4*)(xbf + (size_t)ssrc[j] * 8));
        int dg = ge - gs;
        float inv = 1.0f / (float)(dg > 1 ? dg : 1);
        const float4* xp = (const float4*)(x + (size_t)node * 8);  // self: fp32
        float4 x0 = xp[0], x1v = xp[1];
        ushort* row = xa + (size_t)node * 32;
        uint4 o0 = {pack2(x0.x, x0.y), pack2(x0.z, x0.w),
                    pack2(x1v.x, x1v.y), pack2(x1v.z, x1v.w)};
        uint4 o1 = {pack2(a[0]*inv, a[1]*inv), pack2(a[2]*inv, a[3]*inv),
                    pack2(a[4]*inv, a[5]*inv), pack2(a[6]*inv, a[7]*inv)};
        uint4 zz = {0u, 0u, 0u, 0u};
        *(uint4*)(row)      = o0;
        *(uint4*)(row + 8)  = o1;
        *(uint4*)(row + 16) = zz;
        *(uint4*)(row + 24) = zz;
        // z = the bf16-rounded values the MFMA will consume
        z[0] = bflo(o0.x); z[1] = bfhi(o0.x); z[2]  = bflo(o0.y); z[3]  = bfhi(o0.y);
        z[4] = bflo(o0.z); z[5] = bfhi(o0.z); z[6]  = bflo(o0.w); z[7]  = bfhi(o0.w);
        z[8] = bflo(o1.x); z[9] = bfhi(o1.x); z[10] = bflo(o1.y); z[11] = bfhi(o1.y);
        z[12]= bflo(o1.z); z[13]= bfhi(o1.z); z[14] = bflo(o1.w); z[15] = bfhi(o1.w);
    }

    // ---- Gram (tri 136) + S (16): wave-shuffle reduce -> LDS -> slotted glob
    int lane = t & 63;
    #pragma unroll
    for (int i = 0; i < 16; ++i) {
        #pragma unroll
        for (int j = 0; j <= i; ++j) {
            float p = z[i] * z[j];
            p += __shfl_xor(p, 1);  p += __shfl_xor(p, 2);  p += __shfl_xor(p, 4);
            p += __shfl_xor(p, 8);  p += __shfl_xor(p, 16); p += __shfl_xor(p, 32);
            if (lane == 0) atomicAdd(&sG[i * (i + 1) / 2 + j], p);
        }
        float s = z[i];
        s += __shfl_xor(s, 1);  s += __shfl_xor(s, 2);  s += __shfl_xor(s, 4);
        s += __shfl_xor(s, 8);  s += __shfl_xor(s, 16); s += __shfl_xor(s, 32);
        if (lane == 0) atomicAdd(&sG[136 + i], s);
    }
    __syncthreads();
    if (t < GST) atomicAdd(&gram1s[(b & (GSL - 1)) * GST + t], sG[t]);
}

// ---- layer 1: single pass (R11) ---------------------------------------------
// BN stats derived from Gram in the prologue; GEMM runs once, writes x1bf+x1f8.
__global__ void __launch_bounds__(256) k_lin1b(
        const ushort* __restrict__ xa, const ushort* __restrict__ Wcat1,
        const float* __restrict__ b1, const float* __restrict__ gram1s,
        const float* __restrict__ gamma, const float* __restrict__ beta,
        ushort* __restrict__ x1bf, uchar* __restrict__ x1f8) {
    __shared__ ushort sOut[64 * 140];          // stride 140: 4-quad conflict-free
    __shared__ float gG[GST];
    __shared__ float sSc[128], sSh[128];
    int tid = threadIdx.x;
    int wave = tid >> 6, lane = tid & 63;
    int quad = lane >> 4, l16 = lane & 15;
    int n0 = blockIdx.x * 64;

    if (tid < GST) {                           // fold gram slots
        float s = 0.f;
        #pragma unroll
        for (int k = 0; k < GSL; ++k) s += gram1s[k * GST + tid];
        gG[tid] = s;
    }
    __syncthreads();
    if (tid < 128) {                           // stats_f from Gram quadratic
        int f = tid;
        float wv[16];
        #pragma unroll
        for (int k = 0; k < 16; ++k) wv[k] = bf2f(Wcat1[f * 32 + k]);
        float dotS = 0.f;
        #pragma unroll
        for (int k = 0; k < 16; ++k) dotS += wv[k] * gG[136 + k];
        float quad2 = 0.f;
        #pragma unroll
        for (int i = 0; i < 16; ++i) {
            float wi = wv[i];
            quad2 += wi * wi * gG[i * (i + 1) / 2 + i];
            #pragma unroll
            for (int j = 0; j < i; ++j)
                quad2 += 2.f * wi * wv[j] * gG[i * (i + 1) / 2 + j];
        }
        float bb = b1[f];
        float sum   = dotS + (float)N_NODES * bb;
        float sumsq = quad2 + 2.f * bb * dotS + (float)N_NODES * bb * bb;
        float mu  = sum * (1.0f / N_NODES);
        float var = sumsq * (1.0f / N_NODES) - mu * mu;
        var = fmaxf(var, 0.f);
        float sc  = gamma[f] * rsqrtf(var + BN_EPS);
        sSc[f] = sc;
        sSh[f] = beta[f] - mu * sc;
    }
    __syncthreads();

    int node = n0 + wave * 16 + l16;
    int cn = (node < N_NODES) ? node : N_NODES - 1;
    B8 ta;
    ta.u = *(const uint4*)(xa + (size_t)cn * 32 + quad * 8);

    #pragma unroll
    for (int nt = 0; nt < 8; ++nt) {
        int fb = nt * 16 + l16;
        B8 tb;
        tb.u = *(const uint4*)(Wcat1 + fb * 32 + quad * 8);
        f32x4 acc = {0.f, 0.f, 0.f, 0.f};
        acc = __builtin_amdgcn_mfma_f32_16x16x32_bf16(ta.s, tb.s, acc, 0, 0, 0);
        float bb = b1[fb];
        float sc = sSc[fb], sh = sSh[fb];
        #pragma unroll
        for (int r = 0; r < 4; ++r) {
            int row = wave * 16 + quad * 4 + r;
            float y = fmaxf(0.f, (acc[r] + bb) * sc + sh);
            sOut[row * 140 + fb] = f2bf(y);
        }
    }
    __syncthreads();

    #pragma unroll
    for (int p = 0; p < 4; ++p) {
        int row = p * 16 + (tid >> 4);
        int nd = n0 + row;
        if (nd < N_NODES) {
            int c0 = (tid & 15) * 8;
            uint4 v = *(const uint4*)&sOut[row * 140 + c0];
            *(uint4*)(x1bf + (size_t)nd * F + c0) = v;
            float f0 = bflo(v.x), f1 = bfhi(v.x), f2 = bflo(v.y), f3 = bfhi(v.y);
            float f4 = bflo(v.z), f5 = bfhi(v.z), f6 = bflo(v.w), f7 = bfhi(v.w);
            int p0 = __builtin_amdgcn_cvt_pk_fp8_f32(f0, f1, 0, false);
            p0     = __builtin_amdgcn_cvt_pk_fp8_f32(f2, f3, p0, true);
            int p1 = __builtin_amdgcn_cvt_pk_fp8_f32(f4, f5, 0, false);
            p1     = __builtin_amdgcn_cvt_pk_fp8_f32(f6, f7, p1, true);
            uint2 o8 = {(uint)p0, (uint)p1};
            *(uint2*)(x1f8 + (size_t)nd * F + c0) = o8;
        }
    }
}

// ---- layer 2 ---------------------------------------------------------------

// agg2bf[n][f] = bf16(mean over in-edges of fp8 x1f8[src][f]); 8 thr x 16B/node
__global__ void __launch_bounds__(256) k_agg2(
        const uchar* __restrict__ x1f8, const int* __restrict__ offs,
        const int* __restrict__ ssrc, ushort* __restrict__ agg2bf) {
    int t = threadIdx.x;
    int n = blockIdx.x * 32 + (t >> 3);        // 32 nodes/block, N%32==0
    int c16 = (t & 7) * 16;                    // 16 features per thread
    int s0 = offs[n], s1 = offs[n + 1];
    float acc[16];
    #pragma unroll
    for (int i = 0; i < 16; ++i) acc[i] = 0.f;
    int j = s0;
    for (; j + 7 < s1; j += 8) {               // 8 gathers in flight
        int i0 = ssrc[j],   i1 = ssrc[j+1], i2 = ssrc[j+2], i3 = ssrc[j+3];
        int i4 = ssrc[j+4], i5 = ssrc[j+5], i6 = ssrc[j+6], i7 = ssrc[j+7];
        uint4 v0 = *(const uint4*)(x1f8 + (size_t)i0 * F + c16);
        uint4 v1 = *(const uint4*)(x1f8 + (size_t)i1 * F + c16);
        uint4 v2 = *(const uint4*)(x1f8 + (size_t)i2 * F + c16);
        uint4 v3 = *(const uint4*)(x1f8 + (size_t)i3 * F + c16);
        uint4 v4 = *(const uint4*)(x1f8 + (size_t)i4 * F + c16);
        uint4 v5 = *(const uint4*)(x1f8 + (size_t)i5 * F + c16);
        uint4 v6 = *(const uint4*)(x1f8 + (size_t)i6 * F + c16);
        uint4 v7 = *(const uint4*)(x1f8 + (size_t)i7 * F + c16);
        acc4f8(acc, v0.x); acc4f8(acc+4, v0.y); acc4f8(acc+8, v0.z); acc4f8(acc+12, v0.w);
        acc4f8(acc, v1.x); acc4f8(acc+4, v1.y); acc4f8(acc+8, v1.z); acc4f8(acc+12, v1.w);
        acc4f8(acc, v2.x); acc4f8(acc+4, v2.y); acc4f8(acc+8, v2.z); acc4f8(acc+12, v2.w);
        acc4f8(acc, v3.x); acc4f8(acc+4, v3.y); acc4f8(acc+8, v3.z); acc4f8(acc+12, v3.w);
        acc4f8(acc, v4.x); acc4f8(acc+4, v4.y); acc4f8(acc+8, v4.z); acc4f8(acc+12, v4.w);
        acc4f8(acc, v5.x); acc4f8(acc+4, v5.y); acc4f8(acc+8, v5.z); acc4f8(acc+12, v5.w);
        acc4f8(acc, v6.x); acc4f8(acc+4, v6.y); acc4f8(acc+8, v6.z); acc4f8(acc+12, v6.w);
        acc4f8(acc, v7.x); acc4f8(acc+4, v7.y); acc4f8(acc+8, v7.z); acc4f8(acc+12, v7.w);
    }
    for (; j + 3 < s1; j += 4) {
        int i0 = ssrc[j], i1 = ssrc[j+1], i2 = ssrc[j+2], i3 = ssrc[j+3];
        uint4 v0 = *(const uint4*)(x1f8 + (size_t)i0 * F + c16);
        uint4 v1 = *(const uint4*)(x1f8 + (size_t)i1 * F + c16);
        uint4 v2 = *(const uint4*)(x1f8 + (size_t)i2 * F + c16);
        uint4 v3 = *(const uint4*)(x1f8 + (size_t)i3 * F + c16);
        acc4f8(acc, v0.x); acc4f8(acc+4, v0.y); acc4f8(acc+8, v0.z); acc4f8(acc+12, v0.w);
        acc4f8(acc, v1.x); acc4f8(acc+4, v1.y); acc4f8(acc+8, v1.z); acc4f8(acc+12, v1.w);
        acc4f8(acc, v2.x); acc4f8(acc+4, v2.y); acc4f8(acc+8, v2.z); acc4f8(acc+12, v2.w);
        acc4f8(acc, v3.x); acc4f8(acc+4, v3.y); acc4f8(acc+8, v3.z); acc4f8(acc+12, v3.w);
    }
    for (; j < s1; ++j) {
        uint4 v = *(const uint4*)(x1f8 + (size_t)ssrc[j] * F + c16);
        acc4f8(acc, v.x); acc4f8(acc+4, v.y); acc4f8(acc+8, v.z); acc4f8(acc+12, v.w);
    }
    int dg = s1 - s0;
    float inv = 1.0f / (float)(dg > 1 ? dg : 1);
    uint4 o0 = {pack2(acc[0]*inv,  acc[1]*inv),  pack2(acc[2]*inv,  acc[3]*inv),
                pack2(acc[4]*inv,  acc[5]*inv),  pack2(acc[6]*inv,  acc[7]*inv)};
    uint4 o1 = {pack2(acc[8]*inv,  acc[9]*inv),  pack2(acc[10]*inv, acc[11]*inv),
                pack2(acc[12]*inv, acc[13]*inv), pack2(acc[14]*inv, acc[15]*inv)};
    ushort* dst = agg2bf + (size_t)n * F + c16;
    *(uint4*)(dst)     = o0;
    *(uint4*)(dst + 8) = o1;
}

// h2 = agg2 @ W2l^T + b2 + x1 @ W2r^T via bf16 MFMA.
// Structure frozen (R3/R7); stats slotted (R10, the 47us-floor fix).
__device__ inline int gSw(int f, int j) { return (f << 5) | ((j + f) & 31); }

__global__ void __launch_bounds__(256, 2) k_lin2(
        const ushort* __restrict__ agg2bf, const ushort* __restrict__ x1bf,
        const ushort* __restrict__ Wcat, const float* __restrict__ b2,
        ushort* __restrict__ h2bf, float* __restrict__ stats2s) {
    __shared__ ushort sB[2048 * 8];            // 32 KB, swizzled granules (64 f)
    int tid = threadIdx.x;
    int wave = tid >> 6, lane = tid & 63;
    int quad = lane >> 4, l16 = lane & 15;

    // XCD-paired mapping: 782 blocks = 391 node-groups x 2 f-halves.
    int bid = blockIdx.x;
    int ng, fh;
    if (bid < 768) {                           // groups of 16: i and i+8 pair up
        int g = bid >> 4, i = bid & 15;
        ng = g * 8 + (i & 7);                  // 0..383
        fh = i >> 3;
    } else {                                   // tail: 14 blocks, 7 groups
        int idx = bid - 768;
        ng = 384 + (idx >> 1);                 // 384..390
        fh = idx & 1;
    }
    int fbase = fh * 64;
    int wf = wave & 1, grp = wave >> 1;
    int f0 = wf * 32 + l16;                    // LOCAL f within the half, [0,64)
    int f1 = f0 + 16;

    // stage half of Wcat -> LDS (coalesced global; swizzled conflict-free LDS)
    #pragma unroll
    for (int it = 0; it < 8; ++it) {
        int c = it * 256 + tid;                // local 16B-granule index [0,2048)
        int f = c >> 5, j = c & 31;
        uint4 v = *(const uint4*)(Wcat + ((size_t)(fbase + f) * 32 + j) * 8);
        *(uint4*)&sB[gSw(f, j) * 8] = v;
    }
    __syncthreads();

    float bb0 = b2[fbase + f0], bb1 = b2[fbase + f1];
    float s0 = 0.f, s0q = 0.f, s1 = 0.f, s1q = 0.f;
    int n0 = ng * 256 + grp * 128;             // this wave-group's 128 nodes

    s16x8 aA[8], aB[8];                        // one 16-node tile each: 32 VGPR
    auto loadTile = [&](s16x8* a, int nb) {
        int an = nb + l16;
        if (an >= N_NODES) an = N_NODES - 1;   // clamp; stores masked below
        #pragma unroll
        for (int ks = 0; ks < 8; ++ks) {
            const ushort* src = (ks < 4) ? agg2bf : x1bf;
            B8 tm;
            tm.u = *(const uint4*)(src + (size_t)an * F + (ks & 3) * 32 + quad * 8);
            a[ks] = tm.s;
        }
    };
    auto computeTile = [&](s16x8* a, int nb) {
        f32x4 acc0 = {0,0,0,0}, acc1 = {0,0,0,0};
        #pragma unroll
        for (int ks = 0; ks < 8; ++ks) {
            int j = (ks << 2) + quad;
            B8 tb0, tb1;
            tb0.u = *(const uint4*)&sB[gSw(f0, j) * 8];
            tb1.u = *(const uint4*)&sB[gSw(f1, j) * 8];
            acc0 = __builtin_amdgcn_mfma_f32_16x16x32_bf16(a[ks], tb0.s, acc0, 0, 0, 0);
            acc1 = __builtin_amdgcn_mfma_f32_16x16x32_bf16(a[ks], tb1.s, acc1, 0, 0, 0);
        }
        #pragma unroll
        for (int r = 0; r < 4; ++r) {          // C: row=quad*4+r (node), col (f)
            int node = nb + quad * 4 + r;
            if (node < N_NODES) {
                float v0 = acc0[r] + bb0, v1 = acc1[r] + bb1;
                h2bf[(size_t)node * F + fbase + f0] = f2bf(v0);
                h2bf[(size_t)node * F + fbase + f1] = f2bf(v1);
                s0 += v0; s0q += v0 * v0;
                s1 += v1; s1q += v1 * v1;
            }
        }
    };

    loadTile(aA, n0);
    #pragma unroll 1
    for (int p = 0; p < 4; ++p) {              // 8 tiles of 16 nodes, pipelined
        int nb = n0 + p * 32;
        loadTile(aB, nb + 16);
        computeTile(aA, nb);
        if (p < 3) loadTile(aA, nb + 32);
        computeTile(aB, nb + 16);
    }

    // reduce across the 4 quads (same f), then one atomic per f per wave,
    // spread across SL2 slots to break same-address serialization.
    s0  += __shfl_xor(s0, 16);  s0  += __shfl_xor(s0, 32);
    s0q += __shfl_xor(s0q, 16); s0q += __shfl_xor(s0q, 32);
    s1  += __shfl_xor(s1, 16);  s1  += __shfl_xor(s1, 32);
    s1q += __shfl_xor(s1q, 16); s1q += __shfl_xor(s1q, 32);
    if (quad == 0) {
        int slot = (blockIdx.x & (SL2 - 1)) * 256;
        atomicAdd(&stats2s[slot + fbase + f0], s0);
        atomicAdd(&stats2s[slot + 128 + fbase + f0], s0q);
        atomicAdd(&stats2s[slot + fbase + f1], s1);
        atomicAdd(&stats2s[slot + 128 + fbase + f1], s1q);
    }
}

// ---- pooling ---------------------------------------------------------------

// BN2 finalize folded in (slot-summed); two 64-node halves in parallel.
__global__ void k_pool(const ushort* __restrict__ x1bf, const ushort* __restrict__ h2bf,
                       const float* __restrict__ stats2s, const float* __restrict__ gamma2,
                       const float* __restrict__ beta2, const int* __restrict__ batch,
                       float* __restrict__ outacc) {
    int f = threadIdx.x & 127;
    int half = threadIdx.x >> 7;
    float s = 0.f, q = 0.f;
    #pragma unroll
    for (int k = 0; k < SL2; ++k) {
        s += stats2s[k * 256 + f];
        q += stats2s[k * 256 + 128 + f];
    }
    float mu  = s * (1.0f / N_NODES);
    float var = q * (1.0f / N_NODES) - mu * mu;
    float sc  = gamma2[f] * rsqrtf(var + BN_EPS);
    float sh  = beta2[f] - mu * sc;
    int n0 = blockIdx.x * 128 + half * 64;
    if (n0 >= N_NODES) return;
    int n1 = min(n0 + 64, N_NODES);
    float acc = 0.f;
    int curg = batch[n0];
    for (int n = n0; n < n1; ++n) {
        int g = batch[n];
        if (g != curg) {
            atomicAdd(&outacc[curg * F + f], acc);
            acc = 0.f; curg = g;
        }
        float v1 = bf2f(x1bf[(size_t)n * F + f]);
        float v2 = fmaxf(0.f, bf2f(h2bf[(size_t)n * F + f]) * sc + sh);
        acc += v1 + v2;
    }
    atomicAdd(&outacc[curg * F + f], acc);
}

__global__ void k_out(const float* __restrict__ outacc, const int* __restrict__ gstart,
                      float* __restrict__ out) {
    int i = blockIdx.x * 256 + threadIdx.x;
    if (i >= NUM_GRAPHS * F) return;
    int g = i >> 7;
    int c = gstart[g + 1] - gstart[g];
    out[i] = outacc[i] / (float)(c > 1 ? c : 1);
}

}  // namespace

extern "C" void kernel_launch(void* const* d_in, const int* in_sizes, int n_in,
                              void* d_out, int out_size, void* d_ws, size_t ws_size,
                              hipStream_t stream) {
    const float* x     = (const float*)d_in[0];
    const int*   ei    = (const int*)d_in[1];    // [2, E]: row0 = src, row1 = dst
    const int*   batch = (const int*)d_in[2];
    const float* W1l   = (const float*)d_in[3];
    const float* b1    = (const float*)d_in[4];
    const float* W1r   = (const float*)d_in[5];
    const float* g1    = (const float*)d_in[6];
    const float* be1   = (const float*)d_in[7];
    const float* W2l   = (const float*)d_in[8];
    const float* b2    = (const float*)d_in[9];
    const float* W2r   = (const float*)d_in[10];
    const float* g2    = (const float*)d_in[11];
    const float* be2   = (const float*)d_in[12];
    float* out = (float*)d_out;

    char* w = (char*)d_ws;
    size_t o = 0;
    auto alloc = [&](size_t bytes) {
        void* p = w + o;
        o += (bytes + 511) & ~(size_t)511;
        return p;
    };
    int*    offs   = (int*)alloc((size_t)(N_NODES + 1) * 4);
    int*    gcount = (int*)alloc((size_t)NBUCK * CB * 4);
    int*    bsum   = (int*)alloc((size_t)NBUCK * 4);
    int*    ssrc   = (int*)alloc((size_t)N_EDGES * 4);
    uint*   epk    = (uint*)alloc((size_t)N_EDGES * 4);
    int*    gstart = (int*)alloc((NUM_GRAPHS + 1) * 4);
    // gram1s (2432f=9728B), stats2s (2048f=8192B), outacc (16384f=65536B):
    // each a 512B multiple -> contiguous; zeroed as one range from gram1s.
    float*  gram1s  = (float*)alloc((size_t)GRAM_FLOATS * 4);
    float*  stats2s = (float*)alloc((size_t)SL2 * 256 * 4);
    float*  outacc  = (float*)alloc((size_t)NUM_GRAPHS * F * 4);
    ushort* Wcat   = (ushort*)alloc((size_t)F * 256 * 2);
    ushort* Wcat1  = (ushort*)alloc((size_t)F * 32 * 2);
    ushort* xbf    = (ushort*)alloc((size_t)N_NODES * 8 * 2);
    ushort* xa     = (ushort*)alloc((size_t)N_NODES * 32 * 2);
    ushort* x1bf   = (ushort*)alloc((size_t)N_NODES * F * 2);
    uchar*  x1f8   = (uchar*)alloc((size_t)N_NODES * F);
    ushort* agg2bf = (ushort*)alloc((size_t)N_NODES * F * 2);
    ushort* h2bf   = (ushort*)alloc((size_t)N_NODES * F * 2);

    // one mega-dispatch: histA + boundaries + weight packs + xbf + zero-fills
    k_pre<<<PB_TOTAL, 256, 0, stream>>>(ei, gcount, batch, gstart,
                                        W2l, W2r, Wcat, W1l, W1r, Wcat1,
                                        x, xbf, gram1s);

    // CSR-by-dst: scan -> partition -> rank (+ fused agg1 + Gram stats)
    k_scanA<<<NBUCK, 512, 0, stream>>>(gcount, bsum);
    k_part <<<CB, 256, 0, stream>>>(ei, gcount, bsum, epk);
    k_rank <<<NBUCK, 512, 0, stream>>>(epk, bsum, offs, ssrc, x, xbf, xa, gram1s);

    // layer 1: single pass (BN stats from Gram; GEMM + BN + ReLU -> x1bf/x1f8)
    k_lin1b<<<(N_NODES + 63) / 64, 256, 0, stream>>>(xa, Wcat1, b1, gram1s,
                                                     g1, be1, x1bf, x1f8);

    // layer 2 (fp8 gather -> fp32 accum -> bf16 MFMA; slotted stats)
    k_agg2  <<<N_NODES / 32, 256, 0, stream>>>(x1f8, offs, ssrc, agg2bf);
    k_lin2  <<<((N_NODES + 255) / 256) * 2, 256, 0, stream>>>(agg2bf, x1bf, Wcat, b2,
                                                              h2bf, stats2s);

    // residual + pool (bnfin2 folded into k_pool, slot-summed)
    k_pool<<<(N_NODES + 127) / 128, 256, 0, stream>>>(x1bf, h2bf, stats2s,
                                                      g2, be2, batch, outacc);
    k_out <<<(NUM_GRAPHS * F + 255) / 256, 256, 0, stream>>>(outacc, gstart, out);
}

// Round 12
// 269.574 us; speedup vs baseline: 1.0837x; 1.0837x over previous
//
#include <hip/hip_runtime.h>
#include <cstdint>
#include <cstddef>

namespace {

constexpr int N_NODES = 100000;
constexpr int N_EDGES = 1600000;
constexpr int NUM_GRAPHS = 128;
constexpr int F = 128;
constexpr float BN_EPS = 1e-5f;

// bucket sort params: 196 buckets x 512 nodes; 400 chunks x 4000 edges
constexpr int W_BUCK = 512;
constexpr int NBUCK = (N_NODES + W_BUCK - 1) / W_BUCK;  // 196
constexpr int CB = 400;
constexpr int CHUNK = N_EDGES / CB;                      // 4000

// R10: slotted stats (same-address atomic serialization was the hidden 47us
// floor under k_lin2/k_lin1s — fix measured 310->271). R11's Gram-in-k_rank
// REGRESSED (+21us: 900+ serial shfl ops on a 196-block latency-bound grid)
// and is reverted. R12: R10 structure + slot counts doubled (chains 98->49,
// 196->98 per address).
constexpr int SL1 = 32;                        // layer-1 stats slots
constexpr int SL2 = 16;                        // layer-2 stats slots
constexpr int STATS_FLOATS = (SL1 + SL2) * 256;  // 12288

typedef float f32x4 __attribute__((ext_vector_type(4)));
typedef float f32x2 __attribute__((ext_vector_type(2)));
typedef short s16x8 __attribute__((ext_vector_type(8)));
typedef unsigned char uchar;
union B8 { uint4 u; s16x8 s; };

__device__ inline ushort f2bf(float x) {         // RNE fp32 -> bf16
    uint u = __float_as_uint(x);
    u += 0x7fffu + ((u >> 16) & 1u);
    return (ushort)(u >> 16);
}
__device__ inline float bf2f(ushort s) { return __uint_as_float(((uint)s) << 16); }
__device__ inline uint pack2(float lo, float hi) {
    return (uint)f2bf(lo) | ((uint)f2bf(hi) << 16);
}
__device__ inline float bflo(uint u) { return __uint_as_float(u << 16); }
__device__ inline float bfhi(uint u) { return __uint_as_float(u & 0xffff0000u); }

// accumulate 4 fp8 (one u32) into a[0..3] via HW cvt
__device__ inline void acc4f8(float* a, uint u) {
    f32x2 lo = __builtin_amdgcn_cvt_pk_f32_fp8((int)u, false);
    f32x2 hi = __builtin_amdgcn_cvt_pk_f32_fp8((int)u, true);
    a[0] += lo[0]; a[1] += lo[1]; a[2] += hi[0]; a[3] += hi[1];
}
// accumulate one bf16x8 row (uint4) into a[0..7]
__device__ inline void acc8bf(float* a, uint4 v) {
    a[0] += bflo(v.x); a[1] += bfhi(v.x);
    a[2] += bflo(v.y); a[3] += bfhi(v.y);
    a[4] += bflo(v.z); a[5] += bfhi(v.z);
    a[6] += bflo(v.w); a[7] += bfhi(v.w);
}

// ---- k_pre: histA + bound + weight packs + xbf + zero-fills (one dispatch) --

constexpr int PB_HIST  = CB;                       // 400
constexpr int PB_BOUND = (N_NODES + 255) / 256;    // 391
constexpr int PB_PB    = 64;
constexpr int PB_PB1   = 16;
constexpr int PB_PX    = (N_NODES + 255) / 256;    // 391
constexpr int PB_Z     = (STATS_FLOATS + NUM_GRAPHS * F) / 256;  // 112
constexpr int PB_TOTAL = PB_HIST + PB_BOUND + PB_PB + PB_PB1 + PB_PX + PB_Z;

__global__ void __launch_bounds__(256) k_pre(
        const int* __restrict__ ei, int* __restrict__ gcount,
        const int* __restrict__ batch, int* __restrict__ gstart,
        const float* __restrict__ W2l, const float* __restrict__ W2r,
        ushort* __restrict__ Wcat,
        const float* __restrict__ W1l, const float* __restrict__ W1r,
        ushort* __restrict__ Wcat1,
        const float* __restrict__ x, ushort* __restrict__ xbf,
        float* __restrict__ stats, float* __restrict__ outacc) {
    __shared__ int bins[NBUCK];
    int bid = blockIdx.x, t = threadIdx.x;
    if (bid < PB_HIST) {                        // edge-chunk dst histogram
        for (int i = t; i < NBUCK; i += 256) bins[i] = 0;
        __syncthreads();
        int e0 = bid * CHUNK;
        for (int i = t; i < CHUNK; i += 256)
            atomicAdd(&bins[ei[N_EDGES + e0 + i] >> 9], 1);
        __syncthreads();
        for (int i = t; i < NBUCK; i += 256) gcount[i * CB + bid] = bins[i];
        return;
    }
    bid -= PB_HIST;
    if (bid < PB_BOUND) {                       // graph boundaries
        int i = bid * 256 + t;
        if (i >= N_NODES) return;
        int b = batch[i];
        if (i == 0) {
            for (int g = 0; g <= b; ++g) gstart[g] = 0;
        } else {
            int p = batch[i - 1];
            if (p != b) for (int g = p + 1; g <= b; ++g) gstart[g] = i;
        }
        if (i == N_NODES - 1) {
            for (int g = b + 1; g <= NUM_GRAPHS; ++g) gstart[g] = N_NODES;
        }
        return;
    }
    bid -= PB_BOUND;
    if (bid < PB_PB) {                          // Wcat (layer 2 weights, bf16)
        int i = bid * 256 + t;                  // 16384 exact
        int f = i >> 7, k = i & 127;
        Wcat[f * 256 + k]       = f2bf(W2l[i]);
        Wcat[f * 256 + 128 + k] = f2bf(W2r[i]);
        return;
    }
    bid -= PB_PB;
    if (bid < PB_PB1) {                         // Wcat1 (layer 1 weights)
        int i = bid * 256 + t;                  // 4096 exact
        int f = i >> 5, k = i & 31;
        float v = (k < 8) ? W1r[f * 8 + k] : ((k < 16) ? W1l[f * 8 + (k - 8)] : 0.f);
        Wcat1[i] = f2bf(v);
        return;
    }
    bid -= PB_PB1;
    if (bid < PB_PX) {                          // xbf: bf16 copy of x (16B rows)
        int n = bid * 256 + t;
        if (n >= N_NODES) return;
        const float4* xp = (const float4*)(x + (size_t)n * 8);
        float4 x0 = xp[0], x1 = xp[1];
        uint4 o = {pack2(x0.x, x0.y), pack2(x0.z, x0.w),
                   pack2(x1.x, x1.y), pack2(x1.z, x1.w)};
        *(uint4*)(xbf + (size_t)n * 8) = o;
        return;
    }
    bid -= PB_PX;
    {                                           // zero stats slots + outacc
        int i = bid * 256 + t;                  // 28672 exact
        if (i < STATS_FLOATS) stats[i] = 0.f;
        else outacc[i - STATS_FLOATS] = 0.f;
    }
}

// ---- CSR-by-dst via 2-level bucket sort (no global atomics) -----------------

__global__ void __launch_bounds__(512) k_scanA(int* __restrict__ g,
                                               int* __restrict__ bsum) {
    __shared__ int tmp[512];
    int b = blockIdx.x, t = threadIdx.x;
    int v = (t < CB) ? g[b * CB + t] : 0;
    tmp[t] = v;
    __syncthreads();
    #pragma unroll
    for (int d = 1; d < 512; d <<= 1) {
        int u = (t >= d) ? tmp[t - d] : 0;
        __syncthreads();
        tmp[t] += u;
        __syncthreads();
    }
    if (t < CB) g[b * CB + t] = tmp[t] - v;   // local exclusive prefix
    if (t == 511) bsum[b] = tmp[511];         // bucket total (RAW, not scanned)
}

__global__ void __launch_bounds__(256) k_part(const int* __restrict__ ei,
                                              const int* __restrict__ gloc,
                                              const int* __restrict__ bsum,
                                              uint* __restrict__ epk) {
    __shared__ int cur[NBUCK];
    __shared__ int pref[256];
    int t = threadIdx.x;
    int v = (t < NBUCK) ? bsum[t] : 0;        // raw totals
    pref[t] = v;
    __syncthreads();
    #pragma unroll
    for (int d = 1; d < 256; d <<= 1) {
        int u = (t >= d) ? pref[t - d] : 0;
        __syncthreads();
        pref[t] += u;
        __syncthreads();
    }
    if (t < NBUCK) cur[t] = gloc[t * CB + blockIdx.x] + (pref[t] - v); // excl
    __syncthreads();
    int e0 = blockIdx.x * CHUNK;
    for (int i = t; i < CHUNK; i += 256) {
        int d = ei[N_EDGES + e0 + i];
        int s = ei[e0 + i];
        int p = atomicAdd(&cur[d >> 9], 1);
        epk[p] = ((uint)s << 9) | (uint)(d & 511);
    }
}

// k_rank: per-bucket dst ranking + scatter, then the layer-1 mean-gather for
// this bucket's own 512 nodes fused in (block just wrote ssrc[s0..s1) itself).
__global__ void __launch_bounds__(512) k_rank(const uint* __restrict__ epk,
                                              const int* __restrict__ bsum,
                                              int* __restrict__ offs,
                                              int* __restrict__ ssrc,
                                              const float* __restrict__ x,
                                              const ushort* __restrict__ xbf,
                                              ushort* __restrict__ xa) {
    __shared__ int dcnt[W_BUCK];
    __shared__ int tmp[W_BUCK];
    __shared__ int cur[W_BUCK];
    __shared__ int pref[256];
    int b = blockIdx.x, t = threadIdx.x;
    // local scan of raw bucket totals -> inclusive prefix (folded scanB)
    if (t < 256) pref[t] = (t < NBUCK) ? bsum[t] : 0;
    __syncthreads();
    #pragma unroll
    for (int d = 1; d < 256; d <<= 1) {
        int u = (t < 256 && t >= d) ? pref[t - d] : 0;
        __syncthreads();
        if (t < 256) pref[t] += u;
        __syncthreads();
    }
    int s0 = pref[b] - bsum[b];                // exclusive start
    int s1 = pref[b];                          // end
    dcnt[t] = 0;
    __syncthreads();
    for (int i = s0 + t; i < s1; i += 512)
        atomicAdd(&dcnt[epk[i] & 511u], 1);
    __syncthreads();
    int v = dcnt[t];
    tmp[t] = v;
    __syncthreads();
    #pragma unroll
    for (int d = 1; d < 512; d <<= 1) {
        int u = (t >= d) ? tmp[t - d] : 0;
        __syncthreads();
        tmp[t] += u;
        __syncthreads();
    }
    int start = s0 + tmp[t] - v;               // exclusive prefix
    int node = b * W_BUCK + t;
    if (node <= N_NODES) offs[node] = start;   // node==N_NODES: writes offs end
    cur[t] = start;
    __syncthreads();
    for (int i = s0 + t; i < s1; i += 512) {
        uint u = epk[i];
        int p = atomicAdd(&cur[u & 511u], 1);
        ssrc[p] = (int)(u >> 9);
    }

    // ---- fused layer-1 aggregation for node (thread t owns node b*512+t) ----
    __syncthreads();                           // vmcnt(0) drain: ssrc visible
    if (node >= N_NODES) return;
    int gs = start, ge = start + v;
    float a[8];
    #pragma unroll
    for (int i = 0; i < 8; ++i) a[i] = 0.f;
    int j = gs;
    for (; j + 7 < ge; j += 8) {               // 8 gathers in flight
        int i0 = ssrc[j],   i1 = ssrc[j+1], i2 = ssrc[j+2], i3 = ssrc[j+3];
        int i4 = ssrc[j+4], i5 = ssrc[j+5], i6 = ssrc[j+6], i7 = ssrc[j+7];
        uint4 v0 = *(const uint4*)(xbf + (size_t)i0 * 8);
        uint4 v1 = *(const uint4*)(xbf + (size_t)i1 * 8);
        uint4 v2 = *(const uint4*)(xbf + (size_t)i2 * 8);
        uint4 v3 = *(const uint4*)(xbf + (size_t)i3 * 8);
        uint4 v4 = *(const uint4*)(xbf + (size_t)i4 * 8);
        uint4 v5 = *(const uint4*)(xbf + (size_t)i5 * 8);
        uint4 v6 = *(const uint4*)(xbf + (size_t)i6 * 8);
        uint4 v7 = *(const uint4*)(xbf + (size_t)i7 * 8);
        acc8bf(a, v0); acc8bf(a, v1); acc8bf(a, v2); acc8bf(a, v3);
        acc8bf(a, v4); acc8bf(a, v5); acc8bf(a, v6); acc8bf(a, v7);
    }
    for (; j + 3 < ge; j += 4) {
        int i0 = ssrc[j], i1 = ssrc[j+1], i2 = ssrc[j+2], i3 = ssrc[j+3];
        uint4 v0 = *(const uint4*)(xbf + (size_t)i0 * 8);
        uint4 v1 = *(const uint4*)(xbf + (size_t)i1 * 8);
        uint4 v2 = *(const uint4*)(xbf + (size_t)i2 * 8);
        uint4 v3 = *(const uint4*)(xbf + (size_t)i3 * 8);
        acc8bf(a, v0); acc8bf(a, v1); acc8bf(a, v2); acc8bf(a, v3);
    }
    for (; j < ge; ++j)
        acc8bf(a, *(const uint4*)(xbf + (size_t)ssrc[j] * 8));
    int dg = ge - gs;
    float inv = 1.0f / (float)(dg > 1 ? dg : 1);
    const float4* xp = (const float4*)(x + (size_t)node * 8);  // self: fp32
    float4 x0 = xp[0], x1v = xp[1];
    ushort* row = xa + (size_t)node * 32;
    uint4 o0 = {pack2(x0.x, x0.y), pack2(x0.z, x0.w), pack2(x1v.x, x1v.y), pack2(x1v.z, x1v.w)};
    uint4 o1 = {pack2(a[0]*inv, a[1]*inv), pack2(a[2]*inv, a[3]*inv),
                pack2(a[4]*inv, a[5]*inv), pack2(a[6]*inv, a[7]*inv)};
    uint4 z = {0u, 0u, 0u, 0u};
    *(uint4*)(row)      = o0;
    *(uint4*)(row + 8)  = o1;
    *(uint4*)(row + 16) = z;
    *(uint4*)(row + 24) = z;
}

// ---- layer 1: two-pass, slotted stats ---------------------------------------

// pass 1: stats only, atomic into slot (bid % SL1) -> per-address serial
// chain 1563 -> ~49.
__global__ void __launch_bounds__(256) k_lin1s(
        const ushort* __restrict__ xa, const ushort* __restrict__ Wcat1,
        const float* __restrict__ b1, float* __restrict__ stats1s) {
    __shared__ float sred[256];                // [0..127]=sum, [128..255]=sumsq
    int tid = threadIdx.x;
    int wave = tid >> 6, lane = tid & 63;
    int quad = lane >> 4, l16 = lane & 15;
    int n0 = blockIdx.x * 64;
    sred[tid] = 0.f;
    __syncthreads();

    int node = n0 + wave * 16 + l16;
    int cn = (node < N_NODES) ? node : N_NODES - 1;
    B8 ta;
    ta.u = *(const uint4*)(xa + (size_t)cn * 32 + quad * 8);

    #pragma unroll
    for (int nt = 0; nt < 8; ++nt) {
        int fb = nt * 16 + l16;
        B8 tb;
        tb.u = *(const uint4*)(Wcat1 + fb * 32 + quad * 8);
        f32x4 acc = {0.f, 0.f, 0.f, 0.f};
        acc = __builtin_amdgcn_mfma_f32_16x16x32_bf16(ta.s, tb.s, acc, 0, 0, 0);
        float bb = b1[fb];
        float ls = 0.f, lq = 0.f;
        #pragma unroll
        for (int r = 0; r < 4; ++r) {
            int rn = n0 + wave * 16 + quad * 4 + r;
            if (rn < N_NODES) {
                float v = bf2f(f2bf(acc[r] + bb));   // match bf16-rounded h1
                ls += v; lq += v * v;
            }
        }
        ls += __shfl_xor(ls, 16); ls += __shfl_xor(ls, 32);
        lq += __shfl_xor(lq, 16); lq += __shfl_xor(lq, 32);
        if (quad == 0) {
            atomicAdd(&sred[fb], ls);
            atomicAdd(&sred[128 + fb], lq);
        }
    }
    __syncthreads();
    atomicAdd(&stats1s[(blockIdx.x & (SL1 - 1)) * 256 + tid], sred[tid]);
}

// pass 2: recompute h1, BN+ReLU from slot-summed stats, write x1bf + x1f8.
__global__ void __launch_bounds__(256) k_lin1b(
        const ushort* __restrict__ xa, const ushort* __restrict__ Wcat1,
        const float* __restrict__ b1, const float* __restrict__ stats1s,
        const float* __restrict__ gamma, const float* __restrict__ beta,
        ushort* __restrict__ x1bf, uchar* __restrict__ x1f8) {
    __shared__ ushort sOut[64 * 140];          // stride 140: 4-quad conflict-free
    __shared__ float sSc[128], sSh[128];
    int tid = threadIdx.x;
    int wave = tid >> 6, lane = tid & 63;
    int quad = lane >> 4, l16 = lane & 15;
    int n0 = blockIdx.x * 64;

    if (tid < 128) {                           // fold slot-sum + BN finalize
        float s = 0.f, q = 0.f;
        #pragma unroll
        for (int k = 0; k < SL1; ++k) {
            s += stats1s[k * 256 + tid];
            q += stats1s[k * 256 + 128 + tid];
        }
        float mu  = s * (1.0f / N_NODES);
        float var = q * (1.0f / N_NODES) - mu * mu;
        float sc  = gamma[tid] * rsqrtf(var + BN_EPS);
        sSc[tid] = sc;
        sSh[tid] = beta[tid] - mu * sc;
    }
    __syncthreads();

    int node = n0 + wave * 16 + l16;
    int cn = (node < N_NODES) ? node : N_NODES - 1;
    B8 ta;
    ta.u = *(const uint4*)(xa + (size_t)cn * 32 + quad * 8);

    #pragma unroll
    for (int nt = 0; nt < 8; ++nt) {
        int fb = nt * 16 + l16;
        B8 tb;
        tb.u = *(const uint4*)(Wcat1 + fb * 32 + quad * 8);
        f32x4 acc = {0.f, 0.f, 0.f, 0.f};
        acc = __builtin_amdgcn_mfma_f32_16x16x32_bf16(ta.s, tb.s, acc, 0, 0, 0);
        float bb = b1[fb];
        float sc = sSc[fb], sh = sSh[fb];
        #pragma unroll
        for (int r = 0; r < 4; ++r) {
            int row = wave * 16 + quad * 4 + r;
            float v = bf2f(f2bf(acc[r] + bb));   // bitwise-same h1 as pass 1
            float y = fmaxf(0.f, v * sc + sh);
            sOut[row * 140 + fb] = f2bf(y);
        }
    }
    __syncthreads();

    #pragma unroll
    for (int p = 0; p < 4; ++p) {
        int row = p * 16 + (tid >> 4);
        int nd = n0 + row;
        if (nd < N_NODES) {
            int c0 = (tid & 15) * 8;
            uint4 v = *(const uint4*)&sOut[row * 140 + c0];
            *(uint4*)(x1bf + (size_t)nd * F + c0) = v;
            float f0 = bflo(v.x), f1 = bfhi(v.x), f2 = bflo(v.y), f3 = bfhi(v.y);
            float f4 = bflo(v.z), f5 = bfhi(v.z), f6 = bflo(v.w), f7 = bfhi(v.w);
            int p0 = __builtin_amdgcn_cvt_pk_fp8_f32(f0, f1, 0, false);
            p0     = __builtin_amdgcn_cvt_pk_fp8_f32(f2, f3, p0, true);
            int p1 = __builtin_amdgcn_cvt_pk_fp8_f32(f4, f5, 0, false);
            p1     = __builtin_amdgcn_cvt_pk_fp8_f32(f6, f7, p1, true);
            uint2 o8 = {(uint)p0, (uint)p1};
            *(uint2*)(x1f8 + (size_t)nd * F + c0) = o8;
        }
    }
}

// ---- layer 2 ---------------------------------------------------------------

// agg2bf[n][f] = bf16(mean over in-edges of fp8 x1f8[src][f]); 8 thr x 16B/node
__global__ void __launch_bounds__(256) k_agg2(
        const uchar* __restrict__ x1f8, const int* __restrict__ offs,
        const int* __restrict__ ssrc, ushort* __restrict__ agg2bf) {
    int t = threadIdx.x;
    int n = blockIdx.x * 32 + (t >> 3);        // 32 nodes/block, N%32==0
    int c16 = (t & 7) * 16;                    // 16 features per thread
    int s0 = offs[n], s1 = offs[n + 1];
    float acc[16];
    #pragma unroll
    for (int i = 0; i < 16; ++i) acc[i] = 0.f;
    int j = s0;
    for (; j + 7 < s1; j += 8) {               // 8 gathers in flight
        int i0 = ssrc[j],   i1 = ssrc[j+1], i2 = ssrc[j+2], i3 = ssrc[j+3];
        int i4 = ssrc[j+4], i5 = ssrc[j+5], i6 = ssrc[j+6], i7 = ssrc[j+7];
        uint4 v0 = *(const uint4*)(x1f8 + (size_t)i0 * F + c16);
        uint4 v1 = *(const uint4*)(x1f8 + (size_t)i1 * F + c16);
        uint4 v2 = *(const uint4*)(x1f8 + (size_t)i2 * F + c16);
        uint4 v3 = *(const uint4*)(x1f8 + (size_t)i3 * F + c16);
        uint4 v4 = *(const uint4*)(x1f8 + (size_t)i4 * F + c16);
        uint4 v5 = *(const uint4*)(x1f8 + (size_t)i5 * F + c16);
        uint4 v6 = *(const uint4*)(x1f8 + (size_t)i6 * F + c16);
        uint4 v7 = *(const uint4*)(x1f8 + (size_t)i7 * F + c16);
        acc4f8(acc, v0.x); acc4f8(acc+4, v0.y); acc4f8(acc+8, v0.z); acc4f8(acc+12, v0.w);
        acc4f8(acc, v1.x); acc4f8(acc+4, v1.y); acc4f8(acc+8, v1.z); acc4f8(acc+12, v1.w);
        acc4f8(acc, v2.x); acc4f8(acc+4, v2.y); acc4f8(acc+8, v2.z); acc4f8(acc+12, v2.w);
        acc4f8(acc, v3.x); acc4f8(acc+4, v3.y); acc4f8(acc+8, v3.z); acc4f8(acc+12, v3.w);
        acc4f8(acc, v4.x); acc4f8(acc+4, v4.y); acc4f8(acc+8, v4.z); acc4f8(acc+12, v4.w);
        acc4f8(acc, v5.x); acc4f8(acc+4, v5.y); acc4f8(acc+8, v5.z); acc4f8(acc+12, v5.w);
        acc4f8(acc, v6.x); acc4f8(acc+4, v6.y); acc4f8(acc+8, v6.z); acc4f8(acc+12, v6.w);
        acc4f8(acc, v7.x); acc4f8(acc+4, v7.y); acc4f8(acc+8, v7.z); acc4f8(acc+12, v7.w);
    }
    for (; j + 3 < s1; j += 4) {
        int i0 = ssrc[j], i1 = ssrc[j+1], i2 = ssrc[j+2], i3 = ssrc[j+3];
        uint4 v0 = *(const uint4*)(x1f8 + (size_t)i0 * F + c16);
        uint4 v1 = *(const uint4*)(x1f8 + (size_t)i1 * F + c16);
        uint4 v2 = *(const uint4*)(x1f8 + (size_t)i2 * F + c16);
        uint4 v3 = *(const uint4*)(x1f8 + (size_t)i3 * F + c16);
        acc4f8(acc, v0.x); acc4f8(acc+4, v0.y); acc4f8(acc+8, v0.z); acc4f8(acc+12, v0.w);
        acc4f8(acc, v1.x); acc4f8(acc+4, v1.y); acc4f8(acc+8, v1.z); acc4f8(acc+12, v1.w);
        acc4f8(acc, v2.x); acc4f8(acc+4, v2.y); acc4f8(acc+8, v2.z); acc4f8(acc+12, v2.w);
        acc4f8(acc, v3.x); acc4f8(acc+4, v3.y); acc4f8(acc+8, v3.z); acc4f8(acc+12, v3.w);
    }
    for (; j < s1; ++j) {
        uint4 v = *(const uint4*)(x1f8 + (size_t)ssrc[j] * F + c16);
        acc4f8(acc, v.x); acc4f8(acc+4, v.y); acc4f8(acc+8, v.z); acc4f8(acc+12, v.w);
    }
    int dg = s1 - s0;
    float inv = 1.0f / (float)(dg > 1 ? dg : 1);
    uint4 o0 = {pack2(acc[0]*inv,  acc[1]*inv),  pack2(acc[2]*inv,  acc[3]*inv),
                pack2(acc[4]*inv,  acc[5]*inv),  pack2(acc[6]*inv,  acc[7]*inv)};
    uint4 o1 = {pack2(acc[8]*inv,  acc[9]*inv),  pack2(acc[10]*inv, acc[11]*inv),
                pack2(acc[12]*inv, acc[13]*inv), pack2(acc[14]*inv, acc[15]*inv)};
    ushort* dst = agg2bf + (size_t)n * F + c16;
    *(uint4*)(dst)     = o0;
    *(uint4*)(dst + 8) = o1;
}

// h2 = agg2 @ W2l^T + b2 + x1 @ W2r^T via bf16 MFMA.
// Structure frozen (R3/R7); stats slotted (R10; SL2 doubled in R12).
__device__ inline int gSw(int f, int j) { return (f << 5) | ((j + f) & 31); }

__global__ void __launch_bounds__(256, 2) k_lin2(
        const ushort* __restrict__ agg2bf, const ushort* __restrict__ x1bf,
        const ushort* __restrict__ Wcat, const float* __restrict__ b2,
        ushort* __restrict__ h2bf, float* __restrict__ stats2s) {
    __shared__ ushort sB[2048 * 8];            // 32 KB, swizzled granules (64 f)
    int tid = threadIdx.x;
    int wave = tid >> 6, lane = tid & 63;
    int quad = lane >> 4, l16 = lane & 15;

    // XCD-paired mapping: 782 blocks = 391 node-groups x 2 f-halves.
    int bid = blockIdx.x;
    int ng, fh;
    if (bid < 768) {                           // groups of 16: i and i+8 pair up
        int g = bid >> 4, i = bid & 15;
        ng = g * 8 + (i & 7);                  // 0..383
        fh = i >> 3;
    } else {                                   // tail: 14 blocks, 7 groups
        int idx = bid - 768;
        ng = 384 + (idx >> 1);                 // 384..390
        fh = idx & 1;
    }
    int fbase = fh * 64;
    int wf = wave & 1, grp = wave >> 1;
    int f0 = wf * 32 + l16;                    // LOCAL f within the half, [0,64)
    int f1 = f0 + 16;

    // stage half of Wcat -> LDS (coalesced global; swizzled conflict-free LDS)
    #pragma unroll
    for (int it = 0; it < 8; ++it) {
        int c = it * 256 + tid;                // local 16B-granule index [0,2048)
        int f = c >> 5, j = c & 31;
        uint4 v = *(const uint4*)(Wcat + ((size_t)(fbase + f) * 32 + j) * 8);
        *(uint4*)&sB[gSw(f, j) * 8] = v;
    }
    __syncthreads();

    float bb0 = b2[fbase + f0], bb1 = b2[fbase + f1];
    float s0 = 0.f, s0q = 0.f, s1 = 0.f, s1q = 0.f;
    int n0 = ng * 256 + grp * 128;             // this wave-group's 128 nodes

    s16x8 aA[8], aB[8];                        // one 16-node tile each: 32 VGPR
    auto loadTile = [&](s16x8* a, int nb) {
        int an = nb + l16;
        if (an >= N_NODES) an = N_NODES - 1;   // clamp; stores masked below
        #pragma unroll
        for (int ks = 0; ks < 8; ++ks) {
            const ushort* src = (ks < 4) ? agg2bf : x1bf;
            B8 tm;
            tm.u = *(const uint4*)(src + (size_t)an * F + (ks & 3) * 32 + quad * 8);
            a[ks] = tm.s;
        }
    };
    auto computeTile = [&](s16x8* a, int nb) {
        f32x4 acc0 = {0,0,0,0}, acc1 = {0,0,0,0};
        #pragma unroll
        for (int ks = 0; ks < 8; ++ks) {
            int j = (ks << 2) + quad;
            B8 tb0, tb1;
            tb0.u = *(const uint4*)&sB[gSw(f0, j) * 8];
            tb1.u = *(const uint4*)&sB[gSw(f1, j) * 8];
            acc0 = __builtin_amdgcn_mfma_f32_16x16x32_bf16(a[ks], tb0.s, acc0, 0, 0, 0);
            acc1 = __builtin_amdgcn_mfma_f32_16x16x32_bf16(a[ks], tb1.s, acc1, 0, 0, 0);
        }
        #pragma unroll
        for (int r = 0; r < 4; ++r) {          // C: row=quad*4+r (node), col (f)
            int node = nb + quad * 4 + r;
            if (node < N_NODES) {
                float v0 = acc0[r] + bb0, v1 = acc1[r] + bb1;
                h2bf[(size_t)node * F + fbase + f0] = f2bf(v0);
                h2bf[(size_t)node * F + fbase + f1] = f2bf(v1);
                s0 += v0; s0q += v0 * v0;
                s1 += v1; s1q += v1 * v1;
            }
        }
    };

    loadTile(aA, n0);
    #pragma unroll 1
    for (int p = 0; p < 4; ++p) {              // 8 tiles of 16 nodes, pipelined
        int nb = n0 + p * 32;
        loadTile(aB, nb + 16);
        computeTile(aA, nb);
        if (p < 3) loadTile(aA, nb + 32);
        computeTile(aB, nb + 16);
    }

    // reduce across the 4 quads (same f), then one atomic per f per wave,
    // spread across SL2 slots to break same-address serialization.
    s0  += __shfl_xor(s0, 16);  s0  += __shfl_xor(s0, 32);
    s0q += __shfl_xor(s0q, 16); s0q += __shfl_xor(s0q, 32);
    s1  += __shfl_xor(s1, 16);  s1  += __shfl_xor(s1, 32);
    s1q += __shfl_xor(s1q, 16); s1q += __shfl_xor(s1q, 32);
    if (quad == 0) {
        int slot = (blockIdx.x & (SL2 - 1)) * 256;
        atomicAdd(&stats2s[slot + fbase + f0], s0);
        atomicAdd(&stats2s[slot + 128 + fbase + f0], s0q);
        atomicAdd(&stats2s[slot + fbase + f1], s1);
        atomicAdd(&stats2s[slot + 128 + fbase + f1], s1q);
    }
}

// ---- pooling ---------------------------------------------------------------

// BN2 finalize folded in (slot-summed); two 64-node halves in parallel.
__global__ void k_pool(const ushort* __restrict__ x1bf, const ushort* __restrict__ h2bf,
                       const float* __restrict__ stats2s, const float* __restrict__ gamma2,
                       const float* __restrict__ beta2, const int* __restrict__ batch,
                       float* __restrict__ outacc) {
    int f = threadIdx.x & 127;
    int half = threadIdx.x >> 7;
    float s = 0.f, q = 0.f;
    #pragma unroll
    for (int k = 0; k < SL2; ++k) {
        s += stats2s[k * 256 + f];
        q += stats2s[k * 256 + 128 + f];
    }
    float mu  = s * (1.0f / N_NODES);
    float var = q * (1.0f / N_NODES) - mu * mu;
    float sc  = gamma2[f] * rsqrtf(var + BN_EPS);
    float sh  = beta2[f] - mu * sc;
    int n0 = blockIdx.x * 128 + half * 64;
    if (n0 >= N_NODES) return;
    int n1 = min(n0 + 64, N_NODES);
    float acc = 0.f;
    int curg = batch[n0];
    for (int n = n0; n < n1; ++n) {
        int g = batch[n];
        if (g != curg) {
            atomicAdd(&outacc[curg * F + f], acc);
            acc = 0.f; curg = g;
        }
        float v1 = bf2f(x1bf[(size_t)n * F + f]);
        float v2 = fmaxf(0.f, bf2f(h2bf[(size_t)n * F + f]) * sc + sh);
        acc += v1 + v2;
    }
    atomicAdd(&outacc[curg * F + f], acc);
}

__global__ void k_out(const float* __restrict__ outacc, const int* __restrict__ gstart,
                      float* __restrict__ out) {
    int i = blockIdx.x * 256 + threadIdx.x;
    if (i >= NUM_GRAPHS * F) return;
    int g = i >> 7;
    int c = gstart[g + 1] - gstart[g];
    out[i] = outacc[i] / (float)(c > 1 ? c : 1);
}

}  // namespace

extern "C" void kernel_launch(void* const* d_in, const int* in_sizes, int n_in,
                              void* d_out, int out_size, void* d_ws, size_t ws_size,
                              hipStream_t stream) {
    const float* x     = (const float*)d_in[0];
    const int*   ei    = (const int*)d_in[1];    // [2, E]: row0 = src, row1 = dst
    const int*   batch = (const int*)d_in[2];
    const float* W1l   = (const float*)d_in[3];
    const float* b1    = (const float*)d_in[4];
    const float* W1r   = (const float*)d_in[5];
    const float* g1    = (const float*)d_in[6];
    const float* be1   = (const float*)d_in[7];
    const float* W2l   = (const float*)d_in[8];
    const float* b2    = (const float*)d_in[9];
    const float* W2r   = (const float*)d_in[10];
    const float* g2    = (const float*)d_in[11];
    const float* be2   = (const float*)d_in[12];
    float* out = (float*)d_out;

    char* w = (char*)d_ws;
    size_t o = 0;
    auto alloc = [&](size_t bytes) {
        void* p = w + o;
        o += (bytes + 511) & ~(size_t)511;
        return p;
    };
    int*    offs   = (int*)alloc((size_t)(N_NODES + 1) * 4);
    int*    gcount = (int*)alloc((size_t)NBUCK * CB * 4);
    int*    bsum   = (int*)alloc((size_t)NBUCK * 4);
    int*    ssrc   = (int*)alloc((size_t)N_EDGES * 4);
    uint*   epk    = (uint*)alloc((size_t)N_EDGES * 4);
    int*    gstart = (int*)alloc((NUM_GRAPHS + 1) * 4);
    float*  stats  = (float*)alloc((size_t)STATS_FLOATS * 4);  // slotted
    ushort* Wcat   = (ushort*)alloc((size_t)F * 256 * 2);
    ushort* Wcat1  = (ushort*)alloc((size_t)F * 32 * 2);
    float*  outacc = (float*)alloc((size_t)NUM_GRAPHS * F * 4);
    ushort* xbf    = (ushort*)alloc((size_t)N_NODES * 8 * 2);
    ushort* xa     = (ushort*)alloc((size_t)N_NODES * 32 * 2);
    ushort* x1bf   = (ushort*)alloc((size_t)N_NODES * F * 2);
    uchar*  x1f8   = (uchar*)alloc((size_t)N_NODES * F);
    ushort* agg2bf = (ushort*)alloc((size_t)N_NODES * F * 2);
    ushort* h2bf   = (ushort*)alloc((size_t)N_NODES * F * 2);

    float* stats1s = stats;                    // 32 slots x 256
    float* stats2s = stats + SL1 * 256;        // 16 slots x 256

    // one mega-dispatch: histA + boundaries + weight packs + xbf + zero-fills
    k_pre<<<PB_TOTAL, 256, 0, stream>>>(ei, gcount, batch, gstart,
                                        W2l, W2r, Wcat, W1l, W1r, Wcat1,
                                        x, xbf, stats, outacc);

    // CSR-by-dst: scan -> partition -> rank (+ fused layer-1 aggregation)
    k_scanA<<<NBUCK, 512, 0, stream>>>(gcount, bsum);
    k_part <<<CB, 256, 0, stream>>>(ei, gcount, bsum, epk);
    k_rank <<<NBUCK, 512, 0, stream>>>(epk, bsum, offs, ssrc, x, xbf, xa);

    // layer 1: two-pass (stats-only slotted, then recompute + BN + ReLU)
    k_lin1s<<<(N_NODES + 63) / 64, 256, 0, stream>>>(xa, Wcat1, b1, stats1s);
    k_lin1b<<<(N_NODES + 63) / 64, 256, 0, stream>>>(xa, Wcat1, b1, stats1s,
                                                     g1, be1, x1bf, x1f8);

    // layer 2 (fp8 gather -> fp32 accum -> bf16 MFMA; slotted stats)
    k_agg2  <<<N_NODES / 32, 256, 0, stream>>>(x1f8, offs, ssrc, agg2bf);
    k_lin2  <<<((N_NODES + 255) / 256) * 2, 256, 0, stream>>>(agg2bf, x1bf, Wcat, b2,
                                                              h2bf, stats2s);

    // residual + pool (bnfin2 folded into k_pool, slot-summed)
    k_pool<<<(N_NODES + 127) / 128, 256, 0, stream>>>(x1bf, h2bf, stats2s,
                                                      g2, be2, batch, outacc);
    k_out <<<(NUM_GRAPHS * F + 255) / 256, 256, 0, stream>>>(outacc, gstart, out);
}